// Round 10
// baseline (229.420 us; speedup 1.0000x reference)
//
#include <hip/hip_runtime.h>

// Problem constants
#define IN_C   64
#define OUT_D  47          // (24-1)*2 - 2*1 + 3
#define XD     24
#define XSP    (XD*XD*XD)  // 13824
#define OSP    (OUT_D*OUT_D*OUT_D) // 103823
#define BATCH  16

// LDS: per-wave halo buffer for a 4x8x8 m-tile: 60 rows (6 z x 10 y),
// row stride RS=12 floats, row r holds x[gz=Bd-1+r/10][gy=Bh-1+r%10][gx=Bw-1..Bw+10]
// at idx 0..11 (only 0..9 ever read).
#define RS     12
#define NR     60
#define WBUF   (NR*RS)     // 720 floats per wave
#define XS_FLOATS 8192     // 32 KB: 8x720 staging (5760) overlaid by 4x2048 reduce

typedef float f4u  __attribute__((ext_vector_type(4), aligned(4)));
typedef float f4a8 __attribute__((ext_vector_type(4), aligned(8)));

// Effective weights: weff[c*64 + (pd*2+dd)*16 + (((ph*2+pw)*2+dh)*2+dw)]
__global__ void weff_prep(const float* __restrict__ w, float* __restrict__ weff) {
    const int tid = threadIdx.x;   // 256
    const int c = tid >> 2;
    const int q = tid & 3;         // q = pd*2+dd
    const int pd = q >> 1, dd = q & 1;
    float wv[27];
    const float* wc = w + (size_t)c * 64 * 27;   // weight[c][0][*]
    #pragma unroll
    for (int z = 0; z < 27; z++) wv[z] = wc[z];
    const int msk[2][2] = {{4, 3}, {6, 1}};
    const int md = msk[pd][dd];
    #pragma unroll
    for (int ph = 0; ph < 2; ph++)
    #pragma unroll
    for (int pw = 0; pw < 2; pw++)
    #pragma unroll
    for (int dh = 0; dh < 2; dh++)
    #pragma unroll
    for (int dw = 0; dw < 2; dw++) {
        const int mh = msk[ph][dh], mw = msk[pw][dw];
        float s = 0.f;
        for (int zd = 0; zd < 3; zd++) if ((md >> zd) & 1)
            for (int zh = 0; zh < 3; zh++) if ((mh >> zh) & 1)
                for (int zw = 0; zw < 3; zw++) if ((mw >> zw) & 1)
                    s += wv[zd * 9 + zh * 3 + zw];
        weff[c * 64 + q * 16 + (((ph * 2 + pw) * 2 + dh) * 2 + dw)] = s;
    }
}

// 864 blocks = 54 sp-tiles (4x8x8 m-space) x 16 n; no channel split ->
// plain stores. XCD-L2 swizzle: b=(braw&7)*108+braw>>3; n=b/54, sp=b%54.
// ROUND-10 SINGLE CHANGE vs R8: 512 threads = 8 waves x 8 channels (was
// 4 waves x 16). Channel-loop body is R8 byte-for-byte (scalar-path
// weights, depth-1 prefetch, wave-private single buffer). Grid wave cap
// rises 42% -> 84% of the machine (all 864 blocks co-resident, 3.375/CU,
// 32KB LDS x4 <= 160KB); halved per-wave convoy count + out-of-phase
// sibling waves fill the lgkmcnt/VALU gaps that R8's 34% VALUBusy exposed.
// Reduction: 3-level tree (8->4->2->1), 32 floats/lane.
__global__ __launch_bounds__(512, 8) void tconv(const float* __restrict__ x,
                                                const float* __restrict__ weff,
                                                const float* __restrict__ bias,
                                                float* __restrict__ out) {
    __shared__ float xs[XS_FLOATS];
    int braw = blockIdx.x;
    int b = (braw & 7) * 108 + (braw >> 3);   // bijective XCD swizzle
    const int n  = b / 54;          // 0..15
    const int sp = b - n * 54;      // 0..53
    const int tz = sp / 9;          // 0..5
    const int r9 = sp - tz * 9;
    const int ty = r9 / 3;
    const int tx = r9 - ty * 3;
    const int Bd = tz * 4, Bh = ty * 8, Bw = tx * 8;

    const int tid = threadIdx.x;
    const int wv  = tid >> 6;       // 0..7
    const int L   = tid & 63;
    const int lz  = L >> 4;         // 0..3  (single m-z)
    const int lyy = (L >> 2) & 3;   // 0..3  (m-y pair)
    const int lxx = L & 3;          // 0..3  (m-x pair)

    float* ws = xs + wv * WBUF;

    // one-time zero fill of the staging region (invalid halo rows read 0)
    #pragma unroll
    for (int i = 0; i < 12; i++) xs[tid + 512 * i] = 0.f;   // covers 0..6143 >= 5760
    __syncthreads();

    // ---- channel-invariant staging descriptors: 3 units/lane ----
    int gofs[3], lad[3], et[3];     // et: -1 skip, 0 full, 1 shift-left, 2 scalar
    #pragma unroll
    for (int k = 0; k < 3; k++) {
        int e = k * 64 + L;
        int u = e / 60;
        int r = e - u * 60;
        int z = r / 10;
        int y = r - z * 10;
        int gz = Bd - 1 + z, gy = Bh - 1 + y;
        bool rv = (e < 180) && ((unsigned)gz < (unsigned)XD) &&
                  ((unsigned)gy < (unsigned)XD);
        int gxs = Bw - 1 + 4 * u;
        int t;
        if (!rv) t = -1;
        else if (gxs < 0) t = 1;          // Bw=0,u=0: gx -1..2
        else if (gxs + 3 > XD - 1) t = 2; // Bw=16,u=2: gx 23..26
        else t = 0;
        et[k] = t;
        gofs[k] = (gz * XD + gy) * XD + (gxs < 0 ? 0 : gxs);
        lad[k] = r * RS + 4 * u;
    }

    const float* xg = x + ((size_t)n * IN_C + wv * 8) * XSP;

    // Wave-uniform weight base on the SCALAR path (s_load -> SGPRs).
    const int wvu = __builtin_amdgcn_readfirstlane(wv);
    const float* Wb = weff + (size_t)wvu * 8 * 64;

    // ---- prologue prefetch: first channel ----
    float4 pre[3];
    #pragma unroll
    for (int k = 0; k < 3; k++) {
        if (et[k] < 0) pre[k] = make_float4(0.f, 0.f, 0.f, 0.f);
        else if (et[k] == 2) pre[k] = make_float4(xg[gofs[k]], 0.f, 0.f, 0.f);
        else { f4u q = *(const f4u*)(xg + gofs[k]);
               pre[k] = make_float4(q.x, q.y, q.z, q.w); }
    }

    float acc[2][2][2][2][2];       // [myi][mxi][pd][ph][pw]
    float* af = &acc[0][0][0][0][0];
    #pragma unroll
    for (int i = 0; i < 32; i++) af[i] = 0.f;

    // lane-fixed row base: rows (lz + za)*10 + (2lyy + ya), x offset 2lxx
    const int rb = (lz * 10 + lyy * 2) * RS + 2 * lxx;

    // ---- barrier-free channel loop (wave-private buffer), 8 channels ----
    #pragma unroll 1
    for (int cc = 0; cc < 8; cc++) {
        #pragma unroll
        for (int k = 0; k < 3; k++) {
            if (et[k] >= 0) {
                float4 c = pre[k];
                if (et[k] == 1) c = make_float4(0.f, c.x, c.y, c.z);
                *(float4*)&ws[lad[k]] = c;
            }
        }
        if (cc + 1 < 8) {
            const float* xc = xg + (size_t)(cc + 1) * XSP;
            #pragma unroll
            for (int k = 0; k < 3; k++) {
                if (et[k] < 0) continue;
                if (et[k] == 2) pre[k] = make_float4(xc[gofs[k]], 0.f, 0.f, 0.f);
                else { f4u q = *(const f4u*)(xc + gofs[k]);
                       pre[k] = make_float4(q.x, q.y, q.z, q.w); }
            }
        }

        const float* Wc = Wb + cc * 64;                  // uniform (SGPR base)
        #pragma unroll
        for (int za = 0; za < 3; za++) {
            float xv[4][4];
            #pragma unroll
            for (int ya = 0; ya < 4; ya++) {
                f4a8 v = *(const f4a8*)&ws[rb + (za * 10 + ya) * RS];
                xv[ya][0] = v.x; xv[ya][1] = v.y;
                xv[ya][2] = v.z; xv[ya][3] = v.w;
            }
            // za = pd + dd
            #pragma unroll
            for (int pd = 0; pd < 2; pd++)
            #pragma unroll
            for (int dd = 0; dd < 2; dd++) {
                if (pd + dd != za) continue;
                const float* Wg = Wc + (pd * 2 + dd) * 16;
                #pragma unroll
                for (int ph = 0; ph < 2; ph++)
                #pragma unroll
                for (int pw = 0; pw < 2; pw++)
                #pragma unroll
                for (int dh = 0; dh < 2; dh++)
                #pragma unroll
                for (int dw = 0; dw < 2; dw++) {
                    const float wgt = Wg[((ph * 2 + pw) * 2 + dh) * 2 + dw];
                    #pragma unroll
                    for (int myi = 0; myi < 2; myi++)
                    #pragma unroll
                    for (int mxi = 0; mxi < 2; mxi++)
                        acc[myi][mxi][pd][ph][pw] +=
                            wgt * xv[myi + ph + dh][mxi + pw + dw];
                }
            }
        }
    }

    // ---- in-block 3-level tree reduction over the 8 waves ----
    __syncthreads();
    // L1: odd waves -> regions 0..3 (2048 floats each); even waves add
    if (wv & 1) {
        float* R = xs + (wv >> 1) * 2048;
        #pragma unroll
        for (int j = 0; j < 8; j++)
            *(float4*)&R[(j * 64 + L) * 4] = *(float4*)&af[j * 4];
    }
    __syncthreads();
    if (!(wv & 1)) {
        const float* R = xs + (wv >> 1) * 2048;
        #pragma unroll
        for (int j = 0; j < 8; j++) {
            float4 v = *(const float4*)&R[(j * 64 + L) * 4];
            af[j * 4 + 0] += v.x; af[j * 4 + 1] += v.y;
            af[j * 4 + 2] += v.z; af[j * 4 + 3] += v.w;
        }
    }
    __syncthreads();
    // L2: waves 2,6 -> regions 0,1; waves 0,4 add
    if (wv == 2 || wv == 6) {
        float* R = xs + (wv >> 2) * 2048;
        #pragma unroll
        for (int j = 0; j < 8; j++)
            *(float4*)&R[(j * 64 + L) * 4] = *(float4*)&af[j * 4];
    }
    __syncthreads();
    if (wv == 0 || wv == 4) {
        const float* R = xs + (wv >> 2) * 2048;
        #pragma unroll
        for (int j = 0; j < 8; j++) {
            float4 v = *(const float4*)&R[(j * 64 + L) * 4];
            af[j * 4 + 0] += v.x; af[j * 4 + 1] += v.y;
            af[j * 4 + 2] += v.z; af[j * 4 + 3] += v.w;
        }
    }
    __syncthreads();
    // L3: wave 4 -> region 0; wave 0 adds + stores
    if (wv == 4) {
        #pragma unroll
        for (int j = 0; j < 8; j++)
            *(float4*)&xs[(j * 64 + L) * 4] = *(float4*)&af[j * 4];
    }
    __syncthreads();
    if (wv == 0) {
        #pragma unroll
        for (int j = 0; j < 8; j++) {
            float4 v = *(const float4*)&xs[(j * 64 + L) * 4];
            af[j * 4 + 0] += v.x; af[j * 4 + 1] += v.y;
            af[j * 4 + 2] += v.z; af[j * 4 + 3] += v.w;
        }

        // ---- epilogue: plain stores by wave 0 ----
        const float b0 = bias[0] * 64.0f;
        float* on = out + (size_t)n * OSP;
        const int mz = Bd + lz;
        #pragma unroll
        for (int pd = 0; pd < 2; pd++) {
            const int od = 2 * mz + pd;
            if (od >= OUT_D) continue;
            #pragma unroll
            for (int myi = 0; myi < 2; myi++)
            #pragma unroll
            for (int ph = 0; ph < 2; ph++) {
                const int oh = 2 * (Bh + 2 * lyy + myi) + ph;
                if (oh >= OUT_D) continue;
                const size_t rowo = ((size_t)od * OUT_D + oh) * OUT_D;
                #pragma unroll
                for (int mxi = 0; mxi < 2; mxi++)
                #pragma unroll
                for (int pw = 0; pw < 2; pw++) {
                    const int ow = 2 * (Bw + 2 * lxx + mxi) + pw;
                    if (ow < OUT_D)
                        on[rowo + ow] =
                            acc[myi][mxi][pd][ph][pw] * 64.0f + b0;
                }
            }
        }
    }
}

extern "C" void kernel_launch(void* const* d_in, const int* in_sizes, int n_in,
                              void* d_out, int out_size, void* d_ws, size_t ws_size,
                              hipStream_t stream) {
    const float* x      = (const float*)d_in[0];
    const float* weight = (const float*)d_in[1];
    const float* bias   = (const float*)d_in[2];
    float* out = (float*)d_out;
    float* weff = (float*)d_ws;        // 64*64 floats = 16 KB

    hipLaunchKernelGGL(weff_prep, dim3(1), dim3(256), 0, stream, weight, weff);

    dim3 grid(54 * BATCH, 1, 1);       // 864 blocks
    hipLaunchKernelGGL(tconv, grid, dim3(512), 0, stream, x, weff, bias, out);
}

// Round 11
// 118.216 us; speedup vs baseline: 1.9407x; 1.9407x over previous
//
#include <hip/hip_runtime.h>

// Problem constants
#define IN_C   64
#define OUT_D  47          // (24-1)*2 - 2*1 + 3
#define XD     24
#define XSP    (XD*XD*XD)  // 13824
#define OSP    (OUT_D*OUT_D*OUT_D) // 103823
#define BATCH  16

// LDS: per-wave halo buffer for a 4x8x8 m-tile: 60 rows (6 z x 10 y),
// row stride RS=12 floats, row r holds x[gz=Bd-1+r/10][gy=Bh-1+r%10][gx=Bw-1..Bw+10]
// at idx 0..11 (only 0..9 ever read).
#define RS     12
#define NR     60
#define WBUF   (NR*RS)     // 720 floats per wave
#define XS_FLOATS 8192     // 32 KB: 8x720 staging (5760) overlaid by 4x2048 reduce

typedef float f4u  __attribute__((ext_vector_type(4), aligned(4)));
typedef float f4a8 __attribute__((ext_vector_type(4), aligned(8)));

// Effective weights: weff[c*64 + (pd*2+dd)*16 + (((ph*2+pw)*2+dh)*2+dw)]
__global__ void weff_prep(const float* __restrict__ w, float* __restrict__ weff) {
    const int tid = threadIdx.x;   // 256
    const int c = tid >> 2;
    const int q = tid & 3;         // q = pd*2+dd
    const int pd = q >> 1, dd = q & 1;
    float wv[27];
    const float* wc = w + (size_t)c * 64 * 27;   // weight[c][0][*]
    #pragma unroll
    for (int z = 0; z < 27; z++) wv[z] = wc[z];
    const int msk[2][2] = {{4, 3}, {6, 1}};
    const int md = msk[pd][dd];
    #pragma unroll
    for (int ph = 0; ph < 2; ph++)
    #pragma unroll
    for (int pw = 0; pw < 2; pw++)
    #pragma unroll
    for (int dh = 0; dh < 2; dh++)
    #pragma unroll
    for (int dw = 0; dw < 2; dw++) {
        const int mh = msk[ph][dh], mw = msk[pw][dw];
        float s = 0.f;
        for (int zd = 0; zd < 3; zd++) if ((md >> zd) & 1)
            for (int zh = 0; zh < 3; zh++) if ((mh >> zh) & 1)
                for (int zw = 0; zw < 3; zw++) if ((mw >> zw) & 1)
                    s += wv[zd * 9 + zh * 3 + zw];
        weff[c * 64 + q * 16 + (((ph * 2 + pw) * 2 + dh) * 2 + dw)] = s;
    }
}

// 864 blocks = 54 sp-tiles (4x8x8 m-space) x 16 n; no channel split ->
// plain stores. XCD-L2 swizzle: b=(braw&7)*108+braw>>3; n=b/54, sp=b%54.
// 512 threads = 8 waves x 8 channels; channel-loop body is R8 byte-for-byte
// (scalar-path weights, depth-1 prefetch, wave-private single buffer).
// ROUND-11 SINGLE FIX vs R10: __launch_bounds__(512, 4) instead of (512, 8).
// R10's (512,8) forced VGPR=32 -> hot-loop scratch spills (WRITE 220 MB).
// The body needs ~48 VGPR (R8-measured); at 48 <= 64 the HARDWARE still
// permits 8 waves/SIMD, so 864 co-resident blocks x 8 waves = 27 waves/CU
// (84% of machine) remain reachable -- without strangling the allocator.
// Grid wave total: 6912 (2x R8's 3456). Same iteration count as R8.
// Reduction: 3-level tree (8->4->2->1), 32 floats/lane.
__global__ __launch_bounds__(512, 4) void tconv(const float* __restrict__ x,
                                                const float* __restrict__ weff,
                                                const float* __restrict__ bias,
                                                float* __restrict__ out) {
    __shared__ float xs[XS_FLOATS];
    int braw = blockIdx.x;
    int b = (braw & 7) * 108 + (braw >> 3);   // bijective XCD swizzle
    const int n  = b / 54;          // 0..15
    const int sp = b - n * 54;      // 0..53
    const int tz = sp / 9;          // 0..5
    const int r9 = sp - tz * 9;
    const int ty = r9 / 3;
    const int tx = r9 - ty * 3;
    const int Bd = tz * 4, Bh = ty * 8, Bw = tx * 8;

    const int tid = threadIdx.x;
    const int wv  = tid >> 6;       // 0..7
    const int L   = tid & 63;
    const int lz  = L >> 4;         // 0..3  (single m-z)
    const int lyy = (L >> 2) & 3;   // 0..3  (m-y pair)
    const int lxx = L & 3;          // 0..3  (m-x pair)

    float* ws = xs + wv * WBUF;

    // one-time zero fill of the staging region (invalid halo rows read 0)
    #pragma unroll
    for (int i = 0; i < 12; i++) xs[tid + 512 * i] = 0.f;   // covers 0..6143 >= 5760
    __syncthreads();

    // ---- channel-invariant staging descriptors: 3 units/lane ----
    int gofs[3], lad[3], et[3];     // et: -1 skip, 0 full, 1 shift-left, 2 scalar
    #pragma unroll
    for (int k = 0; k < 3; k++) {
        int e = k * 64 + L;
        int u = e / 60;
        int r = e - u * 60;
        int z = r / 10;
        int y = r - z * 10;
        int gz = Bd - 1 + z, gy = Bh - 1 + y;
        bool rv = (e < 180) && ((unsigned)gz < (unsigned)XD) &&
                  ((unsigned)gy < (unsigned)XD);
        int gxs = Bw - 1 + 4 * u;
        int t;
        if (!rv) t = -1;
        else if (gxs < 0) t = 1;          // Bw=0,u=0: gx -1..2
        else if (gxs + 3 > XD - 1) t = 2; // Bw=16,u=2: gx 23..26
        else t = 0;
        et[k] = t;
        gofs[k] = (gz * XD + gy) * XD + (gxs < 0 ? 0 : gxs);
        lad[k] = r * RS + 4 * u;
    }

    const float* xg = x + ((size_t)n * IN_C + wv * 8) * XSP;

    // Wave-uniform weight base on the SCALAR path (s_load -> SGPRs).
    const int wvu = __builtin_amdgcn_readfirstlane(wv);
    const float* Wb = weff + (size_t)wvu * 8 * 64;

    // ---- prologue prefetch: first channel ----
    float4 pre[3];
    #pragma unroll
    for (int k = 0; k < 3; k++) {
        if (et[k] < 0) pre[k] = make_float4(0.f, 0.f, 0.f, 0.f);
        else if (et[k] == 2) pre[k] = make_float4(xg[gofs[k]], 0.f, 0.f, 0.f);
        else { f4u q = *(const f4u*)(xg + gofs[k]);
               pre[k] = make_float4(q.x, q.y, q.z, q.w); }
    }

    float acc[2][2][2][2][2];       // [myi][mxi][pd][ph][pw]
    float* af = &acc[0][0][0][0][0];
    #pragma unroll
    for (int i = 0; i < 32; i++) af[i] = 0.f;

    // lane-fixed row base: rows (lz + za)*10 + (2lyy + ya), x offset 2lxx
    const int rb = (lz * 10 + lyy * 2) * RS + 2 * lxx;

    // ---- barrier-free channel loop (wave-private buffer), 8 channels ----
    #pragma unroll 1
    for (int cc = 0; cc < 8; cc++) {
        #pragma unroll
        for (int k = 0; k < 3; k++) {
            if (et[k] >= 0) {
                float4 c = pre[k];
                if (et[k] == 1) c = make_float4(0.f, c.x, c.y, c.z);
                *(float4*)&ws[lad[k]] = c;
            }
        }
        if (cc + 1 < 8) {
            const float* xc = xg + (size_t)(cc + 1) * XSP;
            #pragma unroll
            for (int k = 0; k < 3; k++) {
                if (et[k] < 0) continue;
                if (et[k] == 2) pre[k] = make_float4(xc[gofs[k]], 0.f, 0.f, 0.f);
                else { f4u q = *(const f4u*)(xc + gofs[k]);
                       pre[k] = make_float4(q.x, q.y, q.z, q.w); }
            }
        }

        const float* Wc = Wb + cc * 64;                  // uniform (SGPR base)
        #pragma unroll
        for (int za = 0; za < 3; za++) {
            float xv[4][4];
            #pragma unroll
            for (int ya = 0; ya < 4; ya++) {
                f4a8 v = *(const f4a8*)&ws[rb + (za * 10 + ya) * RS];
                xv[ya][0] = v.x; xv[ya][1] = v.y;
                xv[ya][2] = v.z; xv[ya][3] = v.w;
            }
            // za = pd + dd
            #pragma unroll
            for (int pd = 0; pd < 2; pd++)
            #pragma unroll
            for (int dd = 0; dd < 2; dd++) {
                if (pd + dd != za) continue;
                const float* Wg = Wc + (pd * 2 + dd) * 16;
                #pragma unroll
                for (int ph = 0; ph < 2; ph++)
                #pragma unroll
                for (int pw = 0; pw < 2; pw++)
                #pragma unroll
                for (int dh = 0; dh < 2; dh++)
                #pragma unroll
                for (int dw = 0; dw < 2; dw++) {
                    const float wgt = Wg[((ph * 2 + pw) * 2 + dh) * 2 + dw];
                    #pragma unroll
                    for (int myi = 0; myi < 2; myi++)
                    #pragma unroll
                    for (int mxi = 0; mxi < 2; mxi++)
                        acc[myi][mxi][pd][ph][pw] +=
                            wgt * xv[myi + ph + dh][mxi + pw + dw];
                }
            }
        }
    }

    // ---- in-block 3-level tree reduction over the 8 waves ----
    __syncthreads();
    // L1: odd waves -> regions 0..3 (2048 floats each); even waves add
    if (wv & 1) {
        float* R = xs + (wv >> 1) * 2048;
        #pragma unroll
        for (int j = 0; j < 8; j++)
            *(float4*)&R[(j * 64 + L) * 4] = *(float4*)&af[j * 4];
    }
    __syncthreads();
    if (!(wv & 1)) {
        const float* R = xs + (wv >> 1) * 2048;
        #pragma unroll
        for (int j = 0; j < 8; j++) {
            float4 v = *(const float4*)&R[(j * 64 + L) * 4];
            af[j * 4 + 0] += v.x; af[j * 4 + 1] += v.y;
            af[j * 4 + 2] += v.z; af[j * 4 + 3] += v.w;
        }
    }
    __syncthreads();
    // L2: waves 2,6 -> regions 0,1; waves 0,4 add
    if (wv == 2 || wv == 6) {
        float* R = xs + (wv >> 2) * 2048;
        #pragma unroll
        for (int j = 0; j < 8; j++)
            *(float4*)&R[(j * 64 + L) * 4] = *(float4*)&af[j * 4];
    }
    __syncthreads();
    if (wv == 0 || wv == 4) {
        const float* R = xs + (wv >> 2) * 2048;
        #pragma unroll
        for (int j = 0; j < 8; j++) {
            float4 v = *(const float4*)&R[(j * 64 + L) * 4];
            af[j * 4 + 0] += v.x; af[j * 4 + 1] += v.y;
            af[j * 4 + 2] += v.z; af[j * 4 + 3] += v.w;
        }
    }
    __syncthreads();
    // L3: wave 4 -> region 0; wave 0 adds + stores
    if (wv == 4) {
        #pragma unroll
        for (int j = 0; j < 8; j++)
            *(float4*)&xs[(j * 64 + L) * 4] = *(float4*)&af[j * 4];
    }
    __syncthreads();
    if (wv == 0) {
        #pragma unroll
        for (int j = 0; j < 8; j++) {
            float4 v = *(const float4*)&xs[(j * 64 + L) * 4];
            af[j * 4 + 0] += v.x; af[j * 4 + 1] += v.y;
            af[j * 4 + 2] += v.z; af[j * 4 + 3] += v.w;
        }

        // ---- epilogue: plain stores by wave 0 ----
        const float b0 = bias[0] * 64.0f;
        float* on = out + (size_t)n * OSP;
        const int mz = Bd + lz;
        #pragma unroll
        for (int pd = 0; pd < 2; pd++) {
            const int od = 2 * mz + pd;
            if (od >= OUT_D) continue;
            #pragma unroll
            for (int myi = 0; myi < 2; myi++)
            #pragma unroll
            for (int ph = 0; ph < 2; ph++) {
                const int oh = 2 * (Bh + 2 * lyy + myi) + ph;
                if (oh >= OUT_D) continue;
                const size_t rowo = ((size_t)od * OUT_D + oh) * OUT_D;
                #pragma unroll
                for (int mxi = 0; mxi < 2; mxi++)
                #pragma unroll
                for (int pw = 0; pw < 2; pw++) {
                    const int ow = 2 * (Bw + 2 * lxx + mxi) + pw;
                    if (ow < OUT_D)
                        on[rowo + ow] =
                            acc[myi][mxi][pd][ph][pw] * 64.0f + b0;
                }
            }
        }
    }
}

extern "C" void kernel_launch(void* const* d_in, const int* in_sizes, int n_in,
                              void* d_out, int out_size, void* d_ws, size_t ws_size,
                              hipStream_t stream) {
    const float* x      = (const float*)d_in[0];
    const float* weight = (const float*)d_in[1];
    const float* bias   = (const float*)d_in[2];
    float* out = (float*)d_out;
    float* weff = (float*)d_ws;        // 64*64 floats = 16 KB

    hipLaunchKernelGGL(weff_prep, dim3(1), dim3(256), 0, stream, weight, weff);

    dim3 grid(54 * BATCH, 1, 1);       // 864 blocks
    hipLaunchKernelGGL(tconv, grid, dim3(512), 0, stream, x, weff, bias, out);
}

// Round 12
// 118.105 us; speedup vs baseline: 1.9425x; 1.0009x over previous
//
#include <hip/hip_runtime.h>

// Problem constants
#define IN_C   64
#define OUT_D  47          // (24-1)*2 - 2*1 + 3
#define XD     24
#define XSP    (XD*XD*XD)  // 13824
#define OSP    (OUT_D*OUT_D*OUT_D) // 103823
#define BATCH  16

// LDS: per-wave halo buffer for a 4x8x8 m-tile: 60 rows (6 z x 10 y),
// row stride RS=12 floats, row r holds x[gz=Bd-1+r/10][gy=Bh-1+r%10][gx=Bw-1..Bw+10]
// at idx 0..11 (only 0..9 ever read).
#define RS     12
#define NR     60
#define WBUF   (NR*RS)     // 720 floats per wave

typedef float f4u  __attribute__((ext_vector_type(4), aligned(4)));
typedef float f4a8 __attribute__((ext_vector_type(4), aligned(8)));

// Effective weights: weff[c*64 + (pd*2+dd)*16 + (((ph*2+pw)*2+dh)*2+dw)]
__global__ void weff_prep(const float* __restrict__ w, float* __restrict__ weff) {
    const int tid = threadIdx.x;   // 256
    const int c = tid >> 2;
    const int q = tid & 3;         // q = pd*2+dd
    const int pd = q >> 1, dd = q & 1;
    float wv[27];
    const float* wc = w + (size_t)c * 64 * 27;   // weight[c][0][*]
    #pragma unroll
    for (int z = 0; z < 27; z++) wv[z] = wc[z];
    const int msk[2][2] = {{4, 3}, {6, 1}};
    const int md = msk[pd][dd];
    #pragma unroll
    for (int ph = 0; ph < 2; ph++)
    #pragma unroll
    for (int pw = 0; pw < 2; pw++)
    #pragma unroll
    for (int dh = 0; dh < 2; dh++)
    #pragma unroll
    for (int dw = 0; dw < 2; dw++) {
        const int mh = msk[ph][dh], mw = msk[pw][dw];
        float s = 0.f;
        for (int zd = 0; zd < 3; zd++) if ((md >> zd) & 1)
            for (int zh = 0; zh < 3; zh++) if ((mh >> zh) & 1)
                for (int zw = 0; zw < 3; zw++) if ((mw >> zw) & 1)
                    s += wv[zd * 9 + zh * 3 + zw];
        weff[c * 64 + q * 16 + (((ph * 2 + pw) * 2 + dh) * 2 + dw)] = s;
    }
}

// 864 blocks = 54 sp-tiles (4x8x8 m-space) x 16 n; no channel split ->
// plain stores. XCD-L2 swizzle: b=(braw&7)*108+braw>>3; n=b/54, sp=b%54.
// 256 threads = 4 waves; wave wv reduces channels [16wv,16wv+16) in a
// wave-PRIVATE LDS buffer (no barriers in the channel loop). Lane owns a
// 1x2x2 m-block; scalar-path weights (R8-proven, SGPR~80).
// ROUND-12 SINGLE CHANGE vs R8: hoist all 12 ds_read_b128 into xv[12]
// BEFORE the FMA section. R8 read 4 rows per za-group (3 groups) ->
// 3 x {ds_read, lgkm drain (mixed with weight s_loads -> lgkmcnt(0)),
// FMA} serial exposures per channel. Now: STAGE -> 12 reads -> FETCH ->
// ONE drain -> 256 drain-free FMAs. DS ops are in-order within a wave,
// so reads see the same-channel writes without extra sync.
__global__ __launch_bounds__(256, 4) void tconv(const float* __restrict__ x,
                                                const float* __restrict__ weff,
                                                const float* __restrict__ bias,
                                                float* __restrict__ out) {
    __shared__ float xs[4096];      // 16 KB: 4x720 staging, overlaid 2x2048 reduce
    int braw = blockIdx.x;
    int b = (braw & 7) * 108 + (braw >> 3);   // bijective XCD swizzle
    const int n  = b / 54;          // 0..15
    const int sp = b - n * 54;      // 0..53
    const int tz = sp / 9;          // 0..5
    const int r9 = sp - tz * 9;
    const int ty = r9 / 3;
    const int tx = r9 - ty * 3;
    const int Bd = tz * 4, Bh = ty * 8, Bw = tx * 8;

    const int tid = threadIdx.x;
    const int wv  = tid >> 6;       // 0..3
    const int L   = tid & 63;
    const int lz  = L >> 4;         // 0..3  (single m-z)
    const int lyy = (L >> 2) & 3;   // 0..3  (m-y pair)
    const int lxx = L & 3;          // 0..3  (m-x pair)

    float* ws = xs + wv * WBUF;

    // one-time zero fill (invalid halo rows must read as 0)
    #pragma unroll
    for (int i = 0; i < 16; i++) xs[tid + 256 * i] = 0.f;
    __syncthreads();

    // ---- channel-invariant staging descriptors: 3 units/lane ----
    int gofs[3], lad[3], et[3];     // et: -1 skip, 0 full, 1 shift-left, 2 scalar
    #pragma unroll
    for (int k = 0; k < 3; k++) {
        int e = k * 64 + L;
        int u = e / 60;
        int r = e - u * 60;
        int z = r / 10;
        int y = r - z * 10;
        int gz = Bd - 1 + z, gy = Bh - 1 + y;
        bool rv = (e < 180) && ((unsigned)gz < (unsigned)XD) &&
                  ((unsigned)gy < (unsigned)XD);
        int gxs = Bw - 1 + 4 * u;
        int t;
        if (!rv) t = -1;
        else if (gxs < 0) t = 1;          // Bw=0,u=0: gx -1..2
        else if (gxs + 3 > XD - 1) t = 2; // Bw=16,u=2: gx 23..26
        else t = 0;
        et[k] = t;
        gofs[k] = (gz * XD + gy) * XD + (gxs < 0 ? 0 : gxs);
        lad[k] = r * RS + 4 * u;
    }

    const float* xg = x + ((size_t)n * IN_C + wv * 16) * XSP;

    // Wave-uniform weight base on the SCALAR path (s_load -> SGPRs).
    const int wvu = __builtin_amdgcn_readfirstlane(wv);
    const float* Wb = weff + (size_t)wvu * 16 * 64;

    // ---- prologue prefetch: channel 0 ----
    float4 pre[3];
    #pragma unroll
    for (int k = 0; k < 3; k++) {
        if (et[k] < 0) pre[k] = make_float4(0.f, 0.f, 0.f, 0.f);
        else if (et[k] == 2) pre[k] = make_float4(xg[gofs[k]], 0.f, 0.f, 0.f);
        else { f4u q = *(const f4u*)(xg + gofs[k]);
               pre[k] = make_float4(q.x, q.y, q.z, q.w); }
    }

    float acc[2][2][2][2][2];       // [myi][mxi][pd][ph][pw]
    float* af = &acc[0][0][0][0][0];
    #pragma unroll
    for (int i = 0; i < 32; i++) af[i] = 0.f;

    // lane-fixed row base: rows (lz + za)*10 + (2lyy + ya), x offset 2lxx
    const int rb = (lz * 10 + lyy * 2) * RS + 2 * lxx;

    // ---- barrier-free channel loop (wave-private buffer), 16 channels ----
    #pragma unroll 1
    for (int cc = 0; cc < 16; cc++) {
        // STAGE: 3 ds_write_b128 (in-order with the reads below)
        #pragma unroll
        for (int k = 0; k < 3; k++) {
            if (et[k] >= 0) {
                float4 c = pre[k];
                if (et[k] == 1) c = make_float4(0.f, c.x, c.y, c.z);
                *(float4*)&ws[lad[k]] = c;
            }
        }

        // READ_XV: all 12 ds_read_b128 hoisted -> one latency exposure
        f4a8 xv[12];
        #pragma unroll
        for (int za = 0; za < 3; za++)
        #pragma unroll
        for (int ya = 0; ya < 4; ya++)
            xv[za * 4 + ya] = *(const f4a8*)&ws[rb + (za * 10 + ya) * RS];

        // FETCH next channel (vmcnt path; overlaps the lgkm drain)
        if (cc + 1 < 16) {
            const float* xc = xg + (size_t)(cc + 1) * XSP;
            #pragma unroll
            for (int k = 0; k < 3; k++) {
                if (et[k] < 0) continue;
                if (et[k] == 2) pre[k] = make_float4(xc[gofs[k]], 0.f, 0.f, 0.f);
                else { f4u q = *(const f4u*)(xc + gofs[k]);
                       pre[k] = make_float4(q.x, q.y, q.z, q.w); }
            }
        }

        // FMA section: drain-free after the single lgkm wait
        const float* Wc = Wb + cc * 64;                  // uniform (SGPR base)
        #pragma unroll
        for (int za = 0; za < 3; za++) {
            #pragma unroll
            for (int pd = 0; pd < 2; pd++)
            #pragma unroll
            for (int dd = 0; dd < 2; dd++) {
                if (pd + dd != za) continue;
                const float* Wg = Wc + (pd * 2 + dd) * 16;
                #pragma unroll
                for (int ph = 0; ph < 2; ph++)
                #pragma unroll
                for (int pw = 0; pw < 2; pw++)
                #pragma unroll
                for (int dh = 0; dh < 2; dh++)
                #pragma unroll
                for (int dw = 0; dw < 2; dw++) {
                    const float wgt = Wg[((ph * 2 + pw) * 2 + dh) * 2 + dw];
                    #pragma unroll
                    for (int myi = 0; myi < 2; myi++)
                    #pragma unroll
                    for (int mxi = 0; mxi < 2; mxi++)
                        acc[myi][mxi][pd][ph][pw] +=
                            wgt * xv[za * 4 + myi + ph + dh][mxi + pw + dw];
                }
            }
        }
    }

    // ---- in-block tree reduction over the 4 waves (2 levels, 32 fl/lane) ----
    __syncthreads();
    if (wv == 1 || wv == 3) {
        float* R = xs + (wv >> 1) * 2048;
        #pragma unroll
        for (int j = 0; j < 8; j++)
            *(float4*)&R[(j * 64 + L) * 4] = *(float4*)&af[j * 4];
    }
    __syncthreads();
    if (wv == 0 || wv == 2) {
        const float* R = xs + (wv >> 1) * 2048;
        #pragma unroll
        for (int j = 0; j < 8; j++) {
            float4 v = *(const float4*)&R[(j * 64 + L) * 4];
            af[j * 4 + 0] += v.x; af[j * 4 + 1] += v.y;
            af[j * 4 + 2] += v.z; af[j * 4 + 3] += v.w;
        }
    }
    __syncthreads();
    if (wv == 2) {
        #pragma unroll
        for (int j = 0; j < 8; j++)
            *(float4*)&xs[(j * 64 + L) * 4] = *(float4*)&af[j * 4];
    }
    __syncthreads();
    if (wv == 0) {
        #pragma unroll
        for (int j = 0; j < 8; j++) {
            float4 v = *(const float4*)&xs[(j * 64 + L) * 4];
            af[j * 4 + 0] += v.x; af[j * 4 + 1] += v.y;
            af[j * 4 + 2] += v.z; af[j * 4 + 3] += v.w;
        }

        // ---- epilogue: plain stores by wave 0 ----
        const float b0 = bias[0] * 64.0f;
        float* on = out + (size_t)n * OSP;
        const int mz = Bd + lz;
        #pragma unroll
        for (int pd = 0; pd < 2; pd++) {
            const int od = 2 * mz + pd;
            if (od >= OUT_D) continue;
            #pragma unroll
            for (int myi = 0; myi < 2; myi++)
            #pragma unroll
            for (int ph = 0; ph < 2; ph++) {
                const int oh = 2 * (Bh + 2 * lyy + myi) + ph;
                if (oh >= OUT_D) continue;
                const size_t rowo = ((size_t)od * OUT_D + oh) * OUT_D;
                #pragma unroll
                for (int mxi = 0; mxi < 2; mxi++)
                #pragma unroll
                for (int pw = 0; pw < 2; pw++) {
                    const int ow = 2 * (Bw + 2 * lxx + mxi) + pw;
                    if (ow < OUT_D)
                        on[rowo + ow] =
                            acc[myi][mxi][pd][ph][pw] * 64.0f + b0;
                }
            }
        }
    }
}

extern "C" void kernel_launch(void* const* d_in, const int* in_sizes, int n_in,
                              void* d_out, int out_size, void* d_ws, size_t ws_size,
                              hipStream_t stream) {
    const float* x      = (const float*)d_in[0];
    const float* weight = (const float*)d_in[1];
    const float* bias   = (const float*)d_in[2];
    float* out = (float*)d_out;
    float* weff = (float*)d_ws;        // 64*64 floats = 16 KB

    hipLaunchKernelGGL(weff_prep, dim3(1), dim3(256), 0, stream, weight, weff);

    dim3 grid(54 * BATCH, 1, 1);       // 864 blocks
    hipLaunchKernelGGL(tconv, grid, dim3(256), 0, stream, x, weff, bias, out);
}